// Round 1
// baseline (915.961 us; speedup 1.0000x reference)
//
#include <hip/hip_runtime.h>
#include <math.h>

#define B_N 2048
#define F_N 512
#define H_N 256
#define E_N 64
#define K_TOP 8

// ---------------- K0: prep (transposes, expert norms, coef, zero counts) ----
__global__ __launch_bounds__(256) void k0_prep(
    const float* __restrict__ proj_w, const float* __restrict__ expert_emb,
    const float* __restrict__ expert_features, const float* __restrict__ trust,
    const float* __restrict__ dt, float* __restrict__ pwT,
    float* __restrict__ embT, float* __restrict__ enT,
    float* __restrict__ coef, int* __restrict__ cnt) {
  int bid = blockIdx.x, tid = threadIdx.x;
  if (bid < 512) {
    // pwT[f][h] = proj_w[h][f]
    int idx = bid * 256 + tid;
    int f = idx >> 8, h = idx & 255;
    pwT[idx] = proj_w[h * 512 + f];
    if (bid == 0 && tid < E_N) cnt[tid] = 0;
  } else {
    int e = bid - 512;  // 0..63
    float v0 = expert_features[e * 512 + tid];
    float v1 = expert_features[e * 512 + tid + 256];
    float ss = v0 * v0 + v1 * v1;
    #pragma unroll
    for (int off = 32; off; off >>= 1) ss += __shfl_xor(ss, off);
    __shared__ float parts[4];
    if ((tid & 63) == 0) parts[tid >> 6] = ss;
    __syncthreads();
    float tot = parts[0] + parts[1] + parts[2] + parts[3];
    float inv = 1.0f / fmaxf(sqrtf(tot), 1e-8f);
    enT[tid * 64 + e] = v0 * inv;
    enT[(tid + 256) * 64 + e] = v1 * inv;
    embT[tid * 64 + e] = expert_emb[e * 256 + tid];  // tid<256 == H
    if (tid == 0) {
      float st = fmaxf(0.1f, expf(-0.005f * dt[e]));
      coef[e] = trust[e] * st;
    }
  }
}

// ---------------- K1: score + top-8 + softmax + scatter ---------------------
__global__ __launch_bounds__(256) void k1_score(
    const float* __restrict__ features, const float* __restrict__ proj_b,
    const float* __restrict__ pwT, const float* __restrict__ embT,
    const float* __restrict__ enT, const float* __restrict__ coef,
    int* __restrict__ cnt, int* __restrict__ tk_idx, float* __restrict__ tk_w,
    int* __restrict__ tlist, float* __restrict__ wlist) {
  __shared__ float h_lds[8][256];
  int tid = threadIdx.x;
  int b0 = blockIdx.x * 8;

  // Phase A: h[t][tid] = features[b0+t] . proj_w[tid] + proj_b[tid]
  float pb = proj_b[tid];
  float acc[8];
  #pragma unroll
  for (int t = 0; t < 8; ++t) acc[t] = pb;
  #pragma unroll 4
  for (int f = 0; f < 512; ++f) {
    float pw = pwT[f * 256 + tid];
    #pragma unroll
    for (int t = 0; t < 8; ++t)
      acc[t] = fmaf(features[(b0 + t) * 512 + f], pw, acc[t]);  // uniform -> s_load
  }
  #pragma unroll
  for (int t = 0; t < 8; ++t) h_lds[t][tid] = acc[t];
  __syncthreads();

  // Phase B: one token per wave (2 halves), lane = expert
  int slot = tid >> 6;  // wave id 0..3
  int e = tid & 63;
  float cf = coef[e];
  for (int half = 0; half < 2; ++half) {
    int tok = slot + 4 * half;
    int b = b0 + tok;
    const float* frow = features + (size_t)b * 512;
    // ||features[b]||
    float ss = 0.0f;
    #pragma unroll
    for (int j = 0; j < 8; ++j) {
      float v = frow[e + 64 * j];
      ss = fmaf(v, v, ss);
    }
    #pragma unroll
    for (int off = 32; off; off >>= 1) ss += __shfl_xor(ss, off);
    float inv_n = 1.0f / fmaxf(sqrtf(ss), 1e-8f);
    // gate logit
    float g = 0.0f;
    #pragma unroll 4
    for (int k = 0; k < 256; ++k)
      g = fmaf(h_lds[tok][k], embT[k * 64 + e], g);
    // similarity dot
    float s = 0.0f;
    #pragma unroll 4
    for (int f = 0; f < 512; ++f)
      s = fmaf(frow[f], enT[f * 64 + e], s);  // frow[f] uniform -> s_load
    float gate = 1.0f / (1.0f + expf(-g * 0.0625f));
    float sim = fmaxf(s * inv_n, 0.0f);
    float score = gate * sim * cf;

    // top-8: butterfly max with (value desc, index asc) tie-break
    float cur = score;
    float bv[8];
    int bi[8];
    #pragma unroll
    for (int r = 0; r < 8; ++r) {
      float mv = cur;
      int mi = e;
      #pragma unroll
      for (int off = 1; off < 64; off <<= 1) {
        float ov = __shfl_xor(mv, off);
        int oi = __shfl_xor(mi, off);
        if (ov > mv || (ov == mv && oi < mi)) { mv = ov; mi = oi; }
      }
      bv[r] = mv;
      bi[r] = mi;
      if (e == mi) cur = -1.0f;  // scores are >= 0
    }
    // softmax over the 8 (order-invariant downstream)
    float m0 = bv[0];
    float ex[8];
    float sum = 0.0f;
    #pragma unroll
    for (int r = 0; r < 8; ++r) { ex[r] = expf(bv[r] - m0); sum += ex[r]; }
    float isum = 1.0f / sum;

    if (e < 8) {
      int ir = 0; float er = 0.0f;
      switch (e) {
        case 0: ir = bi[0]; er = ex[0]; break;
        case 1: ir = bi[1]; er = ex[1]; break;
        case 2: ir = bi[2]; er = ex[2]; break;
        case 3: ir = bi[3]; er = ex[3]; break;
        case 4: ir = bi[4]; er = ex[4]; break;
        case 5: ir = bi[5]; er = ex[5]; break;
        case 6: ir = bi[6]; er = ex[6]; break;
        case 7: ir = bi[7]; er = ex[7]; break;
      }
      float wr = er * isum;
      int pos = atomicAdd(&cnt[ir], 1);
      tlist[ir * B_N + pos] = b;
      wlist[ir * B_N + pos] = wr;
      tk_idx[b * 8 + e] = ir;
      tk_w[b * 8 + e] = wr;
    }
  }
}

// ---------------- K2: out[b,:] = sum_k w_k * fst_b[e_k,:]  ------------------
__global__ __launch_bounds__(256) void k2_bias(
    const int* __restrict__ tk_idx, const float* __restrict__ tk_w,
    const float* __restrict__ fst_b, float* __restrict__ out) {
  int b = blockIdx.x, tid = threadIdx.x;
  int ir[8];
  float wr[8];
  #pragma unroll
  for (int r = 0; r < 8; ++r) {
    ir[r] = tk_idx[b * 8 + r];  // uniform -> s_load
    wr[r] = tk_w[b * 8 + r];
  }
  #pragma unroll
  for (int q = 0; q < 2; ++q) {
    int f = tid + q * 256;
    float a = 0.0f;
    #pragma unroll
    for (int r = 0; r < 8; ++r) a = fmaf(wr[r], fst_b[ir[r] * 512 + f], a);
    out[(size_t)b * 512 + f] = a;
  }
}

// ---------------- K3: gathered per-expert FST GEMM + weighted atomic add ----
#define KC 64
__global__ __launch_bounds__(256, 2) void k3_fst(
    const float* __restrict__ features, const float* __restrict__ fst_w,
    const int* __restrict__ cnt, const int* __restrict__ tlist,
    const float* __restrict__ wlist, float* __restrict__ out) {
  __shared__ float Ws[KC][256];  // 64KB: col panel of fst_w[e]
  __shared__ int tl[64];
  __shared__ float wl[64];
  int tid = threadIdx.x;
  int e = blockIdx.x >> 5;
  int tile = blockIdx.x & 31;
  int c_e = cnt[e];
  int t0 = tile * 64;
  if (t0 >= c_e) return;
  if (tid < 64) {
    int t = t0 + tid;
    if (t < c_e) {
      tl[tid] = tlist[e * B_N + t];
      wl[tid] = wlist[e * B_N + t];
    } else {
      tl[tid] = tlist[e * B_N + t0];  // valid address, zero weight
      wl[tid] = 0.0f;
    }
  }
  __syncthreads();

  int tr = tid >> 5;  // 0..7 token group
  int tc = tid & 31;  // 0..31 col group
  int tlv[8];
  int fbase[8];
  float wgt[8];
  #pragma unroll
  for (int j = 0; j < 8; ++j) {
    int t = tr * 8 + j;
    tlv[j] = tl[t];
    fbase[j] = tl[t] * 512;
    wgt[j] = wl[t];
  }
  const float* fw_e = fst_w + (size_t)e * 512 * 512;

  for (int ch = 0; ch < 2; ++ch) {
    int c0 = ch * 256;
    float acc[8][8];
    #pragma unroll
    for (int j = 0; j < 8; ++j)
      #pragma unroll
      for (int i = 0; i < 8; ++i) acc[j][i] = 0.0f;

    for (int kc = 0; kc < 512 / KC; ++kc) {
      int f0 = kc * KC;
      __syncthreads();  // protect Ws from previous readers
      // stage KC x 256 panel (coalesced b128 in, contiguous b128 to LDS)
      #pragma unroll
      for (int p = 0; p < 16; ++p) {
        int fl = p * 4 + (tid >> 6);
        int c4 = (tid & 63) * 4;
        *(float4*)&Ws[fl][c4] =
            *(const float4*)&fw_e[(size_t)(f0 + fl) * 512 + c0 + c4];
      }
      __syncthreads();
      // compute: 8 tokens x 8 cols per thread
      #pragma unroll 4
      for (int f = 0; f < KC; ++f) {
        float fv[8];
        #pragma unroll
        for (int j = 0; j < 8; ++j) fv[j] = features[fbase[j] + f0 + f];
        float4 w0 = *(const float4*)&Ws[f][tc * 4];
        float4 w1 = *(const float4*)&Ws[f][tc * 4 + 128];
        #pragma unroll
        for (int j = 0; j < 8; ++j) {
          acc[j][0] = fmaf(fv[j], w0.x, acc[j][0]);
          acc[j][1] = fmaf(fv[j], w0.y, acc[j][1]);
          acc[j][2] = fmaf(fv[j], w0.z, acc[j][2]);
          acc[j][3] = fmaf(fv[j], w0.w, acc[j][3]);
          acc[j][4] = fmaf(fv[j], w1.x, acc[j][4]);
          acc[j][5] = fmaf(fv[j], w1.y, acc[j][5]);
          acc[j][6] = fmaf(fv[j], w1.z, acc[j][6]);
          acc[j][7] = fmaf(fv[j], w1.w, acc[j][7]);
        }
      }
    }
    // epilogue: weighted atomic accumulate
    #pragma unroll
    for (int j = 0; j < 8; ++j) {
      float w = wgt[j];
      if (w != 0.0f) {
        size_t orow = (size_t)tlv[j] * 512 + c0;
        #pragma unroll
        for (int i = 0; i < 8; ++i) {
          int c = 4 * tc + (i & 3) + 128 * (i >> 2);
          atomicAdd(&out[orow + c], w * acc[j][i]);
        }
      }
    }
  }
}

// ---------------- launch ----------------------------------------------------
extern "C" void kernel_launch(void* const* d_in, const int* in_sizes, int n_in,
                              void* d_out, int out_size, void* d_ws,
                              size_t ws_size, hipStream_t stream) {
  const float* features = (const float*)d_in[0];
  const float* proj_w = (const float*)d_in[1];
  const float* proj_b = (const float*)d_in[2];
  const float* expert_emb = (const float*)d_in[3];
  const float* expert_features = (const float*)d_in[4];
  const float* trust = (const float*)d_in[5];
  const float* dt = (const float*)d_in[6];
  const float* fst_w = (const float*)d_in[7];
  const float* fst_b = (const float*)d_in[8];
  float* out = (float*)d_out;

  float* ws = (float*)d_ws;
  float* pwT = ws;                           // 512*256
  float* embT = pwT + 131072;                // 256*64
  float* enT = embT + 16384;                 // 512*64
  float* coef = enT + 32768;                 // 64
  int* cnt = (int*)(coef + 64);              // 64
  int* tk_idx = cnt + 64;                    // 2048*8
  float* tk_w = (float*)(tk_idx + 16384);    // 2048*8
  int* tlist = (int*)(tk_w + 16384);         // 64*2048
  float* wlist = (float*)(tlist + 131072);   // 64*2048

  hipLaunchKernelGGL(k0_prep, dim3(576), dim3(256), 0, stream, proj_w,
                     expert_emb, expert_features, trust, dt, pwT, embT, enT,
                     coef, cnt);
  hipLaunchKernelGGL(k1_score, dim3(256), dim3(256), 0, stream, features,
                     proj_b, pwT, embT, enT, coef, cnt, tk_idx, tk_w, tlist,
                     wlist);
  hipLaunchKernelGGL(k2_bias, dim3(2048), dim3(256), 0, stream, tk_idx, tk_w,
                     fst_b, out);
  hipLaunchKernelGGL(k3_fst, dim3(2048), dim3(256), 0, stream, features, fst_w,
                     cnt, tlist, wlist, out);
}

// Round 2
// 446.584 us; speedup vs baseline: 2.0510x; 2.0510x over previous
//
#include <hip/hip_runtime.h>
#include <math.h>

#define B_N 2048
#define F_N 512
#define H_N 256
#define E_N 64
#define K_TOP 8

// ---------------- K0: prep (transposes, expert norms, coef, zero counts) ----
__global__ __launch_bounds__(256) void k0_prep(
    const float* __restrict__ proj_w, const float* __restrict__ expert_emb,
    const float* __restrict__ expert_features, const float* __restrict__ trust,
    const float* __restrict__ dt, float* __restrict__ pwT,
    float* __restrict__ embT, float* __restrict__ enT,
    float* __restrict__ coef, int* __restrict__ cnt) {
  int bid = blockIdx.x, tid = threadIdx.x;
  if (bid < 512) {
    // pwT[f][h] = proj_w[h][f]
    int idx = bid * 256 + tid;
    int f = idx >> 8, h = idx & 255;
    pwT[idx] = proj_w[h * 512 + f];
    if (bid == 0 && tid < E_N) cnt[tid] = 0;
  } else {
    int e = bid - 512;  // 0..63
    float v0 = expert_features[e * 512 + tid];
    float v1 = expert_features[e * 512 + tid + 256];
    float ss = v0 * v0 + v1 * v1;
    #pragma unroll
    for (int off = 32; off; off >>= 1) ss += __shfl_xor(ss, off);
    __shared__ float parts[4];
    if ((tid & 63) == 0) parts[tid >> 6] = ss;
    __syncthreads();
    float tot = parts[0] + parts[1] + parts[2] + parts[3];
    float inv = 1.0f / fmaxf(sqrtf(tot), 1e-8f);
    enT[tid * 64 + e] = v0 * inv;
    enT[(tid + 256) * 64 + e] = v1 * inv;
    embT[tid * 64 + e] = expert_emb[e * 256 + tid];  // tid<256 == H
    if (tid == 0) {
      float st = fmaxf(0.1f, expf(-0.005f * dt[e]));
      coef[e] = trust[e] * st;
    }
  }
}

// ---------------- K1: score + top-8 + softmax + scatter ---------------------
__global__ __launch_bounds__(256) void k1_score(
    const float* __restrict__ features, const float* __restrict__ proj_b,
    const float* __restrict__ pwT, const float* __restrict__ embT,
    const float* __restrict__ enT, const float* __restrict__ coef,
    int* __restrict__ cnt, int* __restrict__ tk_idx, float* __restrict__ tk_w,
    int* __restrict__ tlist, float* __restrict__ wlist) {
  __shared__ float h_lds[8][256];
  int tid = threadIdx.x;
  int b0 = blockIdx.x * 8;

  // Phase A: h[t][tid] = features[b0+t] . proj_w[tid] + proj_b[tid]
  float pb = proj_b[tid];
  float acc[8];
  #pragma unroll
  for (int t = 0; t < 8; ++t) acc[t] = pb;
  #pragma unroll 4
  for (int f = 0; f < 512; ++f) {
    float pw = pwT[f * 256 + tid];
    #pragma unroll
    for (int t = 0; t < 8; ++t)
      acc[t] = fmaf(features[(b0 + t) * 512 + f], pw, acc[t]);  // uniform -> s_load
  }
  #pragma unroll
  for (int t = 0; t < 8; ++t) h_lds[t][tid] = acc[t];
  __syncthreads();

  // Phase B: one token per wave (2 halves), lane = expert
  int slot = tid >> 6;  // wave id 0..3
  int e = tid & 63;
  float cf = coef[e];
  for (int half = 0; half < 2; ++half) {
    int tok = slot + 4 * half;
    int b = b0 + tok;
    const float* frow = features + (size_t)b * 512;
    // ||features[b]||
    float ss = 0.0f;
    #pragma unroll
    for (int j = 0; j < 8; ++j) {
      float v = frow[e + 64 * j];
      ss = fmaf(v, v, ss);
    }
    #pragma unroll
    for (int off = 32; off; off >>= 1) ss += __shfl_xor(ss, off);
    float inv_n = 1.0f / fmaxf(sqrtf(ss), 1e-8f);
    // gate logit
    float g = 0.0f;
    #pragma unroll 4
    for (int k = 0; k < 256; ++k)
      g = fmaf(h_lds[tok][k], embT[k * 64 + e], g);
    // similarity dot
    float s = 0.0f;
    #pragma unroll 4
    for (int f = 0; f < 512; ++f)
      s = fmaf(frow[f], enT[f * 64 + e], s);  // frow[f] uniform -> s_load
    float gate = 1.0f / (1.0f + expf(-g * 0.0625f));
    float sim = fmaxf(s * inv_n, 0.0f);
    float score = gate * sim * cf;

    // top-8: butterfly max with (value desc, index asc) tie-break
    float cur = score;
    float bv[8];
    int bi[8];
    #pragma unroll
    for (int r = 0; r < 8; ++r) {
      float mv = cur;
      int mi = e;
      #pragma unroll
      for (int off = 1; off < 64; off <<= 1) {
        float ov = __shfl_xor(mv, off);
        int oi = __shfl_xor(mi, off);
        if (ov > mv || (ov == mv && oi < mi)) { mv = ov; mi = oi; }
      }
      bv[r] = mv;
      bi[r] = mi;
      if (e == mi) cur = -1.0f;  // scores are >= 0
    }
    // softmax over the 8 (order-invariant downstream)
    float m0 = bv[0];
    float ex[8];
    float sum = 0.0f;
    #pragma unroll
    for (int r = 0; r < 8; ++r) { ex[r] = expf(bv[r] - m0); sum += ex[r]; }
    float isum = 1.0f / sum;

    if (e < 8) {
      int ir = 0; float er = 0.0f;
      switch (e) {
        case 0: ir = bi[0]; er = ex[0]; break;
        case 1: ir = bi[1]; er = ex[1]; break;
        case 2: ir = bi[2]; er = ex[2]; break;
        case 3: ir = bi[3]; er = ex[3]; break;
        case 4: ir = bi[4]; er = ex[4]; break;
        case 5: ir = bi[5]; er = ex[5]; break;
        case 6: ir = bi[6]; er = ex[6]; break;
        case 7: ir = bi[7]; er = ex[7]; break;
      }
      float wr = er * isum;
      int pos = atomicAdd(&cnt[ir], 1);
      tlist[ir * B_N + pos] = b;
      wlist[ir * B_N + pos] = wr;
      tk_idx[b * 8 + e] = ir;
      tk_w[b * 8 + e] = wr;
    }
  }
}

// ---------------- K2: out[b,:] = sum_k w_k * fst_b[e_k,:]  ------------------
__global__ __launch_bounds__(256) void k2_bias(
    const int* __restrict__ tk_idx, const float* __restrict__ tk_w,
    const float* __restrict__ fst_b, float* __restrict__ out) {
  int b = blockIdx.x, tid = threadIdx.x;
  int ir[8];
  float wr[8];
  #pragma unroll
  for (int r = 0; r < 8; ++r) {
    ir[r] = tk_idx[b * 8 + r];  // uniform -> s_load
    wr[r] = tk_w[b * 8 + r];
  }
  #pragma unroll
  for (int q = 0; q < 2; ++q) {
    int f = tid + q * 256;
    float a = 0.0f;
    #pragma unroll
    for (int r = 0; r < 8; ++r) a = fmaf(wr[r], fst_b[ir[r] * 512 + f], a);
    out[(size_t)b * 512 + f] = a;
  }
}

// ---------------- K3: gathered per-expert FST GEMM, double-buffered ---------
// Tile: TM=64 tokens x TN=256 cols per block, 256 threads, micro 8x8.
// W panel staged async (global_load_lds x16B), features chunk staged via regs.
#define TM 64
#define TN 256
#define KC 16

__global__ __launch_bounds__(256, 2) void k3_fst(
    const float* __restrict__ features, const float* __restrict__ fst_w,
    const int* __restrict__ cnt, const int* __restrict__ tlist,
    const float* __restrict__ wlist, float* __restrict__ out) {
  __shared__ float Ws[2][KC][TN];   // 32 KB
  __shared__ float Ft[2][KC][TM];   // 8 KB
  __shared__ int tl[TM];
  __shared__ float wl[TM];

  int tid = threadIdx.x;
  int e = blockIdx.x & 63;          // expert-minor: actives spread across CUs
  int rest = blockIdx.x >> 6;       // 0..63
  int tile = rest >> 1;             // 0..31
  int ch = rest & 1;
  int c0 = ch * TN;
  int c_e = cnt[e];
  int t0 = tile * TM;
  if (t0 >= c_e) return;

  if (tid < TM) {
    int t = t0 + tid;
    if (t < c_e) {
      tl[tid] = tlist[e * B_N + t];
      wl[tid] = wlist[e * B_N + t];
    } else {
      tl[tid] = tlist[e * B_N + t0];  // valid address, zero weight
      wl[tid] = 0.0f;
    }
  }
  __syncthreads();

  const float* fw_e = fst_w + (size_t)e * (512 * 512);
  int wave = tid >> 6, lane = tid & 63;
  int tg = wave * 2 + (lane >> 5);  // token group 0..7
  int cg = lane & 31;               // col group 0..31

  int ft_t = tid >> 2;              // 0..63: token for Ft staging
  int ft_fq = tid & 3;              // 0..3:  f-quad for Ft staging
  const float* ft_src_row = features + (size_t)tl[ft_t] * 512;

  // async stage one KCxTN W panel: each wave-instr fills one 1KB row
  auto stageWs = [&](int kc, int buf) {
    int f0 = kc * KC;
    #pragma unroll
    for (int r = 0; r < 4; ++r) {
      int f = wave * 4 + r;
      const float* src = fw_e + (size_t)(f0 + f) * 512 + c0 + lane * 4;
      __builtin_amdgcn_global_load_lds(
          (const __attribute__((address_space(1))) void*)src,
          (__attribute__((address_space(3))) void*)&Ws[buf][f][0], 16, 0, 0);
    }
  };
  auto loadFt = [&](int kc) -> float4 {
    return *(const float4*)&ft_src_row[kc * KC + ft_fq * 4];
  };
  auto writeFt = [&](float4 v, int buf) {
    Ft[buf][ft_fq * 4 + 0][ft_t] = v.x;
    Ft[buf][ft_fq * 4 + 1][ft_t] = v.y;
    Ft[buf][ft_fq * 4 + 2][ft_t] = v.z;
    Ft[buf][ft_fq * 4 + 3][ft_t] = v.w;
  };

  float acc[8][8];
  #pragma unroll
  for (int j = 0; j < 8; ++j)
    #pragma unroll
    for (int i = 0; i < 8; ++i) acc[j][i] = 0.0f;

  auto compute = [&](int buf) {
    #pragma unroll 4
    for (int f = 0; f < KC; ++f) {
      float4 a0 = *(const float4*)&Ft[buf][f][tg * 8];       // broadcast
      float4 a1 = *(const float4*)&Ft[buf][f][tg * 8 + 4];   // broadcast
      float4 w0 = *(const float4*)&Ws[buf][f][cg * 4];       // lane-contig
      float4 w1 = *(const float4*)&Ws[buf][f][cg * 4 + 128]; // lane-contig
      float av[8] = {a0.x, a0.y, a0.z, a0.w, a1.x, a1.y, a1.z, a1.w};
      float wv[8] = {w0.x, w0.y, w0.z, w0.w, w1.x, w1.y, w1.z, w1.w};
      #pragma unroll
      for (int j = 0; j < 8; ++j)
        #pragma unroll
        for (int i = 0; i < 8; ++i)
          acc[j][i] = fmaf(av[j], wv[i], acc[j][i]);
    }
  };

  // prologue: fill buffer 0
  stageWs(0, 0);
  float4 rf = loadFt(0);
  writeFt(rf, 0);
  __syncthreads();  // drains vmcnt (incl. async lds loads)

  for (int kc = 0; kc < 32; ++kc) {
    int cb = kc & 1, nb = cb ^ 1;
    float4 rn = make_float4(0.f, 0.f, 0.f, 0.f);
    if (kc < 31) {
      stageWs(kc + 1, nb);   // async, lands during compute
      rn = loadFt(kc + 1);   // in-flight during compute
    }
    compute(cb);
    if (kc < 31) writeFt(rn, nb);
    __syncthreads();
  }

  // epilogue: weighted atomic accumulate
  #pragma unroll
  for (int j = 0; j < 8; ++j) {
    int lt = tg * 8 + j;
    float w = wl[lt];
    if (w != 0.0f) {
      size_t orow = (size_t)tl[lt] * 512 + c0 + cg * 4;
      #pragma unroll
      for (int i = 0; i < 4; ++i) atomicAdd(&out[orow + i], w * acc[j][i]);
      #pragma unroll
      for (int i = 0; i < 4; ++i)
        atomicAdd(&out[orow + 128 + i], w * acc[j][i + 4]);
    }
  }
}

// ---------------- launch ----------------------------------------------------
extern "C" void kernel_launch(void* const* d_in, const int* in_sizes, int n_in,
                              void* d_out, int out_size, void* d_ws,
                              size_t ws_size, hipStream_t stream) {
  const float* features = (const float*)d_in[0];
  const float* proj_w = (const float*)d_in[1];
  const float* proj_b = (const float*)d_in[2];
  const float* expert_emb = (const float*)d_in[3];
  const float* expert_features = (const float*)d_in[4];
  const float* trust = (const float*)d_in[5];
  const float* dt = (const float*)d_in[6];
  const float* fst_w = (const float*)d_in[7];
  const float* fst_b = (const float*)d_in[8];
  float* out = (float*)d_out;

  float* ws = (float*)d_ws;
  float* pwT = ws;                           // 512*256
  float* embT = pwT + 131072;                // 256*64
  float* enT = embT + 16384;                 // 512*64
  float* coef = enT + 32768;                 // 64
  int* cnt = (int*)(coef + 64);              // 64
  int* tk_idx = cnt + 64;                    // 2048*8
  float* tk_w = (float*)(tk_idx + 16384);    // 2048*8
  int* tlist = (int*)(tk_w + 16384);         // 64*2048
  float* wlist = (float*)(tlist + 131072);   // 64*2048

  hipLaunchKernelGGL(k0_prep, dim3(576), dim3(256), 0, stream, proj_w,
                     expert_emb, expert_features, trust, dt, pwT, embT, enT,
                     coef, cnt);
  hipLaunchKernelGGL(k1_score, dim3(256), dim3(256), 0, stream, features,
                     proj_b, pwT, embT, enT, coef, cnt, tk_idx, tk_w, tlist,
                     wlist);
  hipLaunchKernelGGL(k2_bias, dim3(2048), dim3(256), 0, stream, tk_idx, tk_w,
                     fst_b, out);
  hipLaunchKernelGGL(k3_fst, dim3(4096), dim3(256), 0, stream, features, fst_w,
                     cnt, tlist, wlist, out);
}

// Round 3
// 242.380 us; speedup vs baseline: 3.7790x; 1.8425x over previous
//
#include <hip/hip_runtime.h>
#include <math.h>

#define B_N 2048
#define F_N 512
#define H_N 256
#define E_N 64

typedef __attribute__((ext_vector_type(8))) short short8;
typedef __attribute__((ext_vector_type(4))) float f32x4;
typedef __attribute__((ext_vector_type(4))) unsigned short ushort4v;

static __device__ __forceinline__ unsigned short bf16_rne(float x) {
  unsigned u = __float_as_uint(x);
  unsigned r = (u + 0x7FFFu + ((u >> 16) & 1u)) >> 16;
  return (unsigned short)r;
}
static __device__ __forceinline__ float bf16_to_f(unsigned short h) {
  return __uint_as_float(((unsigned)h) << 16);
}

// ---------------- K0: prep (transposes, expert norms, coef, zero counts) ----
__global__ __launch_bounds__(256) void k0_prep(
    const float* __restrict__ proj_w, const float* __restrict__ expert_emb,
    const float* __restrict__ expert_features, const float* __restrict__ trust,
    const float* __restrict__ dt, float* __restrict__ pwT,
    float* __restrict__ embT, float* __restrict__ enT,
    float* __restrict__ coef, int* __restrict__ cnt) {
  int bid = blockIdx.x, tid = threadIdx.x;
  if (bid < 512) {
    int idx = bid * 256 + tid;
    int f = idx >> 8, h = idx & 255;
    pwT[idx] = proj_w[h * 512 + f];
    if (bid == 0 && tid < E_N) cnt[tid] = 0;
  } else {
    int e = bid - 512;  // 0..63
    float v0 = expert_features[e * 512 + tid];
    float v1 = expert_features[e * 512 + tid + 256];
    float ss = v0 * v0 + v1 * v1;
    #pragma unroll
    for (int off = 32; off; off >>= 1) ss += __shfl_xor(ss, off);
    __shared__ float parts[4];
    if ((tid & 63) == 0) parts[tid >> 6] = ss;
    __syncthreads();
    float tot = parts[0] + parts[1] + parts[2] + parts[3];
    float inv = 1.0f / fmaxf(sqrtf(tot), 1e-8f);
    enT[tid * 64 + e] = v0 * inv;
    enT[(tid + 256) * 64 + e] = v1 * inv;
    embT[tid * 64 + e] = expert_emb[e * 256 + tid];
    if (tid == 0) {
      float st = fmaxf(0.1f, expf(-0.005f * dt[e]));
      coef[e] = trust[e] * st;
    }
  }
}

// ---------------- conv: features -> bf16 hi/lo -----------------------------
__global__ __launch_bounds__(256) void k_convF(const float* __restrict__ f,
    unsigned short* __restrict__ Fh, unsigned short* __restrict__ Fl) {
  int i = (blockIdx.x * 256 + threadIdx.x) * 4;
  float4 v = *(const float4*)(f + i);
  float xs[4] = {v.x, v.y, v.z, v.w};
  ushort4v h, l;
  #pragma unroll
  for (int j = 0; j < 4; ++j) {
    unsigned short hh = bf16_rne(xs[j]);
    h[j] = hh;
    l[j] = bf16_rne(xs[j] - bf16_to_f(hh));
  }
  *(ushort4v*)(Fh + i) = h;
  *(ushort4v*)(Fl + i) = l;
}

// ---------------- conv: fst_w -> transposed bf16 hi/lo [e][col][k] ----------
__global__ __launch_bounds__(256) void k_convW(const float* __restrict__ fst_w,
    unsigned short* __restrict__ WhT, unsigned short* __restrict__ WlT) {
  int bid = blockIdx.x;           // 2048 = 64e x 8colblk x 4kblk
  int e = bid >> 5;
  int cb = (bid >> 2) & 7;
  int kb = bid & 3;
  int tid = threadIdx.x;
  int col = cb * 64 + (tid & 63);
  int k0 = kb * 128 + (tid >> 6) * 32;
  const float* src = fst_w + ((size_t)e << 18) + (size_t)k0 * 512 + col;
  size_t dbase = ((size_t)e << 18) + (size_t)col * 512 + k0;
  #pragma unroll
  for (int g = 0; g < 4; ++g) {
    short8 vh, vl;
    #pragma unroll
    for (int i = 0; i < 8; ++i) {
      float x = src[(size_t)(g * 8 + i) * 512];   // lane-coalesced (lane->col)
      unsigned short hh = bf16_rne(x);
      vh[i] = (short)hh;
      vl[i] = (short)bf16_rne(x - bf16_to_f(hh));
    }
    *(short8*)(WhT + dbase + g * 8) = vh;
    *(short8*)(WlT + dbase + g * 8) = vl;
  }
}

// ---------------- K1: score + top-8 + softmax + scatter (4 tok/block) -------
__global__ __launch_bounds__(256) void k1_score(
    const float* __restrict__ features, const float* __restrict__ proj_b,
    const float* __restrict__ pwT, const float* __restrict__ embT,
    const float* __restrict__ enT, const float* __restrict__ coef,
    int* __restrict__ cnt, int* __restrict__ tk_idx, float* __restrict__ tk_w,
    int* __restrict__ tlist, float* __restrict__ wlist) {
  __shared__ float h_lds[4][256];
  int tid = threadIdx.x;
  int b0 = blockIdx.x * 4;

  float pb = proj_b[tid];
  float a0 = pb, a1 = pb, a2 = pb, a3 = pb;
  #pragma unroll 4
  for (int f = 0; f < 512; ++f) {
    float pw = pwT[f * 256 + tid];
    a0 = fmaf(features[(b0 + 0) * 512 + f], pw, a0);  // uniform -> s_load
    a1 = fmaf(features[(b0 + 1) * 512 + f], pw, a1);
    a2 = fmaf(features[(b0 + 2) * 512 + f], pw, a2);
    a3 = fmaf(features[(b0 + 3) * 512 + f], pw, a3);
  }
  h_lds[0][tid] = a0; h_lds[1][tid] = a1;
  h_lds[2][tid] = a2; h_lds[3][tid] = a3;
  __syncthreads();

  int tok = tid >> 6;  // one token per wave
  int e = tid & 63;
  float cf = coef[e];
  int b = b0 + tok;
  const float* frow = features + (size_t)b * 512;
  float ss = 0.0f;
  #pragma unroll
  for (int j = 0; j < 8; ++j) {
    float v = frow[e + 64 * j];
    ss = fmaf(v, v, ss);
  }
  #pragma unroll
  for (int off = 32; off; off >>= 1) ss += __shfl_xor(ss, off);
  float inv_n = 1.0f / fmaxf(sqrtf(ss), 1e-8f);
  float g = 0.0f;
  #pragma unroll 4
  for (int k = 0; k < 256; ++k)
    g = fmaf(h_lds[tok][k], embT[k * 64 + e], g);
  float s = 0.0f;
  #pragma unroll 4
  for (int f = 0; f < 512; ++f)
    s = fmaf(frow[f], enT[f * 64 + e], s);  // frow[f] uniform -> s_load
  float gate = 1.0f / (1.0f + expf(-g * 0.0625f));
  float sim = fmaxf(s * inv_n, 0.0f);
  float score = gate * sim * cf;

  float cur = score;
  float bv[8];
  int bi[8];
  #pragma unroll
  for (int r = 0; r < 8; ++r) {
    float mv = cur;
    int mi = e;
    #pragma unroll
    for (int off = 1; off < 64; off <<= 1) {
      float ov = __shfl_xor(mv, off);
      int oi = __shfl_xor(mi, off);
      if (ov > mv || (ov == mv && oi < mi)) { mv = ov; mi = oi; }
    }
    bv[r] = mv;
    bi[r] = mi;
    if (e == mi) cur = -1.0f;
  }
  float m0 = bv[0];
  float ex[8];
  float sum = 0.0f;
  #pragma unroll
  for (int r = 0; r < 8; ++r) { ex[r] = expf(bv[r] - m0); sum += ex[r]; }
  float isum = 1.0f / sum;

  if (e < 8) {
    int ir = 0; float er = 0.0f;
    switch (e) {
      case 0: ir = bi[0]; er = ex[0]; break;
      case 1: ir = bi[1]; er = ex[1]; break;
      case 2: ir = bi[2]; er = ex[2]; break;
      case 3: ir = bi[3]; er = ex[3]; break;
      case 4: ir = bi[4]; er = ex[4]; break;
      case 5: ir = bi[5]; er = ex[5]; break;
      case 6: ir = bi[6]; er = ex[6]; break;
      case 7: ir = bi[7]; er = ex[7]; break;
    }
    float wr = er * isum;
    int pos = atomicAdd(&cnt[ir], 1);
    tlist[ir * B_N + pos] = b;
    wlist[ir * B_N + pos] = wr;
    tk_idx[b * 8 + e] = ir;
    tk_w[b * 8 + e] = wr;
  }
}

// ---------------- K2: out[b,:] = sum_k w_k * fst_b[e_k,:]  ------------------
__global__ __launch_bounds__(256) void k2_bias(
    const int* __restrict__ tk_idx, const float* __restrict__ tk_w,
    const float* __restrict__ fst_b, float* __restrict__ out) {
  int b = blockIdx.x, tid = threadIdx.x;
  int ir[8];
  float wr[8];
  #pragma unroll
  for (int r = 0; r < 8; ++r) {
    ir[r] = tk_idx[b * 8 + r];
    wr[r] = tk_w[b * 8 + r];
  }
  #pragma unroll
  for (int q = 0; q < 2; ++q) {
    int f = tid + q * 256;
    float a = 0.0f;
    #pragma unroll
    for (int r = 0; r < 8; ++r) a = fmaf(wr[r], fst_b[ir[r] * 512 + f], a);
    out[(size_t)b * 512 + f] = a;
  }
}

// ---------------- K3 (MFMA): gathered per-expert FST, bf16 3-term split -----
// Block: 64 tokens x 128 cols x K=512. 4 waves, wave tile M64xN32.
// LDS single-buffered: Bh/Bl[128][64], Ah/Al[64][64] bf16, XOR-swizzled slots.
__global__ __launch_bounds__(256, 3) void k3_mfma(
    const unsigned short* __restrict__ Fh, const unsigned short* __restrict__ Fl,
    const unsigned short* __restrict__ WhT, const unsigned short* __restrict__ WlT,
    const int* __restrict__ cnt, const int* __restrict__ tlist,
    const float* __restrict__ wlist, float* __restrict__ out) {
  __shared__ unsigned short Bh[128 * 64];
  __shared__ unsigned short Bl[128 * 64];
  __shared__ unsigned short Ah[64 * 64];
  __shared__ unsigned short Al[64 * 64];
  __shared__ int tl[64];
  __shared__ float wl[64];

  int tid = threadIdx.x;
  int e = blockIdx.x & 63;          // expert-minor spread
  int rest = blockIdx.x >> 6;
  int chunk = rest & 3;             // 4 col chunks of 128
  int tile = rest >> 2;             // 0..31 token tiles
  int c0 = chunk * 128;
  int c_e = cnt[e];
  int t0 = tile * 64;
  if (t0 >= c_e) return;

  if (tid < 64) {
    int t = t0 + tid;
    tl[tid] = tlist[e * B_N + (t < c_e ? t : t0)];
    wl[tid] = (t < c_e) ? wlist[e * B_N + t] : 0.0f;
  }
  __syncthreads();

  int wave = tid >> 6, lane = tid & 63;
  const unsigned short* WhT_e = WhT + ((size_t)e << 18);
  const unsigned short* WlT_e = WlT + ((size_t)e << 18);

  // staging source offsets (shorts), pre-swizzled so LDS layout is
  // row-major with k-slot p holding logical k-group g = p ^ (row&7)
  size_t bsrc[4];
  int bdst[4];
  #pragma unroll
  for (int i = 0; i < 4; ++i) {
    int cw = wave * 32 + i * 8;           // 8 cols per instr
    int cl = cw + (lane >> 3);
    int g = (lane & 7) ^ (cl & 7);
    bsrc[i] = (size_t)(c0 + cl) * 512 + g * 8;
    bdst[i] = cw * 64;                    // wave-uniform LDS base
  }
  size_t asrc[2];
  int adst[2];
  #pragma unroll
  for (int j = 0; j < 2; ++j) {
    int tw = wave * 16 + j * 8;
    int tkl = tw + (lane >> 3);
    int g = (lane & 7) ^ (tkl & 7);
    asrc[j] = (size_t)tl[tkl] * 512 + g * 8;
    adst[j] = tw * 64;
  }

  f32x4 acc[4][2];
  #pragma unroll
  for (int mt = 0; mt < 4; ++mt)
    #pragma unroll
    for (int ct = 0; ct < 2; ++ct) acc[mt][ct] = (f32x4){0.f, 0.f, 0.f, 0.f};

  int kg = lane >> 4;  // 0..3 k-subgroup within frag
  int mrow = lane & 15;

  #define STAGE(K0S)                                                          \
    do {                                                                      \
      _Pragma("unroll")                                                       \
      for (int i = 0; i < 4; ++i) {                                           \
        __builtin_amdgcn_global_load_lds(                                     \
            (const __attribute__((address_space(1))) void*)(WhT_e + bsrc[i] + (K0S)), \
            (__attribute__((address_space(3))) void*)(Bh + bdst[i]), 16, 0, 0);\
        __builtin_amdgcn_global_load_lds(                                     \
            (const __attribute__((address_space(1))) void*)(WlT_e + bsrc[i] + (K0S)), \
            (__attribute__((address_space(3))) void*)(Bl + bdst[i]), 16, 0, 0);\
      }                                                                       \
      _Pragma("unroll")                                                       \
      for (int j = 0; j < 2; ++j) {                                           \
        __builtin_amdgcn_global_load_lds(                                     \
            (const __attribute__((address_space(1))) void*)(Fh + asrc[j] + (K0S)), \
            (__attribute__((address_space(3))) void*)(Ah + adst[j]), 16, 0, 0);\
        __builtin_amdgcn_global_load_lds(                                     \
            (const __attribute__((address_space(1))) void*)(Fl + asrc[j] + (K0S)), \
            (__attribute__((address_space(3))) void*)(Al + adst[j]), 16, 0, 0);\
      }                                                                       \
    } while (0)

  STAGE(0);
  __syncthreads();

  for (int s = 0; s < 8; ++s) {
    #pragma unroll
    for (int kh = 0; kh < 2; ++kh) {
      int gq = kh * 4 + kg;  // logical k-group 0..7
      short8 afh[4], afl[4], bfh[2], bfl[2];
      #pragma unroll
      for (int mt = 0; mt < 4; ++mt) {
        int tr = mt * 16 + mrow;
        int off = tr * 64 + ((gq ^ (tr & 7)) * 8);
        afh[mt] = *(const short8*)(Ah + off);
        afl[mt] = *(const short8*)(Al + off);
      }
      #pragma unroll
      for (int ct = 0; ct < 2; ++ct) {
        int cl = wave * 32 + ct * 16 + mrow;
        int off = cl * 64 + ((gq ^ (cl & 7)) * 8);
        bfh[ct] = *(const short8*)(Bh + off);
        bfl[ct] = *(const short8*)(Bl + off);
      }
      #pragma unroll
      for (int mt = 0; mt < 4; ++mt)
        #pragma unroll
        for (int ct = 0; ct < 2; ++ct) {
          acc[mt][ct] = __builtin_amdgcn_mfma_f32_16x16x32_bf16(
              afh[mt], bfh[ct], acc[mt][ct], 0, 0, 0);
          acc[mt][ct] = __builtin_amdgcn_mfma_f32_16x16x32_bf16(
              afh[mt], bfl[ct], acc[mt][ct], 0, 0, 0);
          acc[mt][ct] = __builtin_amdgcn_mfma_f32_16x16x32_bf16(
              afl[mt], bfh[ct], acc[mt][ct], 0, 0, 0);
        }
    }
    __syncthreads();                       // all waves done reading panel
    if (s < 7) {
      STAGE((s + 1) * 64);
      __syncthreads();                     // vmcnt drained before reads
    }
  }
  #undef STAGE

  // epilogue: C/D layout col=lane&15, row=(lane>>4)*4+r (m89-verified)
  int rbase = (lane >> 4) * 4;
  #pragma unroll
  for (int mt = 0; mt < 4; ++mt) {
    #pragma unroll
    for (int r = 0; r < 4; ++r) {
      int tloc = mt * 16 + rbase + r;
      float w = wl[tloc];
      if (w != 0.0f) {
        size_t orow = (size_t)tl[tloc] * 512 + c0 + wave * 32 + mrow;
        atomicAdd(out + orow, w * acc[mt][0][r]);
        atomicAdd(out + orow + 16, w * acc[mt][1][r]);
      }
    }
  }
}

// ---------------- K3 fallback (fp32 VALU, round-2 version) ------------------
#define TM 64
#define TN 256
#define KC 16
__global__ __launch_bounds__(256, 2) void k3_fst(
    const float* __restrict__ features, const float* __restrict__ fst_w,
    const int* __restrict__ cnt, const int* __restrict__ tlist,
    const float* __restrict__ wlist, float* __restrict__ out) {
  __shared__ float Ws[2][KC][TN];
  __shared__ float Ft[2][KC][TM];
  __shared__ int tl[TM];
  __shared__ float wl[TM];

  int tid = threadIdx.x;
  int e = blockIdx.x & 63;
  int rest = blockIdx.x >> 6;
  int tile = rest >> 1;
  int ch = rest & 1;
  int c0 = ch * TN;
  int c_e = cnt[e];
  int t0 = tile * TM;
  if (t0 >= c_e) return;

  if (tid < TM) {
    int t = t0 + tid;
    if (t < c_e) {
      tl[tid] = tlist[e * B_N + t];
      wl[tid] = wlist[e * B_N + t];
    } else {
      tl[tid] = tlist[e * B_N + t0];
      wl[tid] = 0.0f;
    }
  }
  __syncthreads();

  const float* fw_e = fst_w + (size_t)e * (512 * 512);
  int wave = tid >> 6, lane = tid & 63;
  int tg = wave * 2 + (lane >> 5);
  int cg = lane & 31;
  int ft_t = tid >> 2;
  int ft_fq = tid & 3;
  const float* ft_src_row = features + (size_t)tl[ft_t] * 512;

  auto stageWs = [&](int kc, int buf) {
    int f0 = kc * KC;
    #pragma unroll
    for (int r = 0; r < 4; ++r) {
      int f = wave * 4 + r;
      const float* src = fw_e + (size_t)(f0 + f) * 512 + c0 + lane * 4;
      __builtin_amdgcn_global_load_lds(
          (const __attribute__((address_space(1))) void*)src,
          (__attribute__((address_space(3))) void*)&Ws[buf][f][0], 16, 0, 0);
    }
  };
  auto loadFt = [&](int kc) -> float4 {
    return *(const float4*)&ft_src_row[kc * KC + ft_fq * 4];
  };
  auto writeFt = [&](float4 v, int buf) {
    Ft[buf][ft_fq * 4 + 0][ft_t] = v.x;
    Ft[buf][ft_fq * 4 + 1][ft_t] = v.y;
    Ft[buf][ft_fq * 4 + 2][ft_t] = v.z;
    Ft[buf][ft_fq * 4 + 3][ft_t] = v.w;
  };

  float acc[8][8];
  #pragma unroll
  for (int j = 0; j < 8; ++j)
    #pragma unroll
    for (int i = 0; i < 8; ++i) acc[j][i] = 0.0f;

  auto compute = [&](int buf) {
    #pragma unroll 4
    for (int f = 0; f < KC; ++f) {
      float4 a0 = *(const float4*)&Ft[buf][f][tg * 8];
      float4 a1 = *(const float4*)&Ft[buf][f][tg * 8 + 4];
      float4 w0 = *(const float4*)&Ws[buf][f][cg * 4];
      float4 w1 = *(const float4*)&Ws[buf][f][cg * 4 + 128];
      float av[8] = {a0.x, a0.y, a0.z, a0.w, a1.x, a1.y, a1.z, a1.w};
      float wv[8] = {w0.x, w0.y, w0.z, w0.w, w1.x, w1.y, w1.z, w1.w};
      #pragma unroll
      for (int j = 0; j < 8; ++j)
        #pragma unroll
        for (int i = 0; i < 8; ++i)
          acc[j][i] = fmaf(av[j], wv[i], acc[j][i]);
    }
  };

  stageWs(0, 0);
  float4 rf = loadFt(0);
  writeFt(rf, 0);
  __syncthreads();

  for (int kc = 0; kc < 32; ++kc) {
    int cb = kc & 1, nb = cb ^ 1;
    float4 rn = make_float4(0.f, 0.f, 0.f, 0.f);
    if (kc < 31) {
      stageWs(kc + 1, nb);
      rn = loadFt(kc + 1);
    }
    compute(cb);
    if (kc < 31) writeFt(rn, nb);
    __syncthreads();
  }

  #pragma unroll
  for (int j = 0; j < 8; ++j) {
    int lt = tg * 8 + j;
    float w = wl[lt];
    if (w != 0.0f) {
      size_t orow = (size_t)tl[lt] * 512 + c0 + cg * 4;
      #pragma unroll
      for (int i = 0; i < 4; ++i) atomicAdd(&out[orow + i], w * acc[j][i]);
      #pragma unroll
      for (int i = 0; i < 4; ++i)
        atomicAdd(&out[orow + 128 + i], w * acc[j][i + 4]);
    }
  }
}

// ---------------- launch ----------------------------------------------------
extern "C" void kernel_launch(void* const* d_in, const int* in_sizes, int n_in,
                              void* d_out, int out_size, void* d_ws,
                              size_t ws_size, hipStream_t stream) {
  const float* features = (const float*)d_in[0];
  const float* proj_w = (const float*)d_in[1];
  const float* proj_b = (const float*)d_in[2];
  const float* expert_emb = (const float*)d_in[3];
  const float* expert_features = (const float*)d_in[4];
  const float* trust = (const float*)d_in[5];
  const float* dt = (const float*)d_in[6];
  const float* fst_w = (const float*)d_in[7];
  const float* fst_b = (const float*)d_in[8];
  float* out = (float*)d_out;

  float* ws = (float*)d_ws;
  float* pwT = ws;                           // 512*256
  float* embT = pwT + 131072;                // 256*64
  float* enT = embT + 16384;                 // 512*64
  float* coef = enT + 32768;                 // 64
  int* cnt = (int*)(coef + 64);              // 64
  int* tk_idx = cnt + 64;                    // 2048*8
  float* tk_w = (float*)(tk_idx + 16384);    // 2048*8
  int* tlist = (int*)(tk_w + 16384);         // 64*2048
  float* wlist = (float*)(tlist + 131072);   // 64*2048
  unsigned short* Fh = (unsigned short*)(wlist + 131072);   // 2048*512
  unsigned short* Fl = Fh + (1 << 20);
  unsigned short* WhT = Fl + (1 << 20);                     // 64*512*512
  unsigned short* WlT = WhT + (1 << 24);
  // bytes needed for MFMA path:
  size_t need = (size_t)((char*)(WlT + (1 << 24)) - (char*)d_ws);
  bool big = ws_size >= need;

  hipLaunchKernelGGL(k0_prep, dim3(576), dim3(256), 0, stream, proj_w,
                     expert_emb, expert_features, trust, dt, pwT, embT, enT,
                     coef, cnt);
  if (big) {
    hipLaunchKernelGGL(k_convF, dim3(1024), dim3(256), 0, stream, features, Fh,
                       Fl);
    hipLaunchKernelGGL(k_convW, dim3(2048), dim3(256), 0, stream, fst_w, WhT,
                       WlT);
  }
  hipLaunchKernelGGL(k1_score, dim3(512), dim3(256), 0, stream, features,
                     proj_b, pwT, embT, enT, coef, cnt, tk_idx, tk_w, tlist,
                     wlist);
  hipLaunchKernelGGL(k2_bias, dim3(2048), dim3(256), 0, stream, tk_idx, tk_w,
                     fst_b, out);
  if (big) {
    hipLaunchKernelGGL(k3_mfma, dim3(8192), dim3(256), 0, stream, Fh, Fl, WhT,
                       WlT, cnt, tlist, wlist, out);
  } else {
    hipLaunchKernelGGL(k3_fst, dim3(4096), dim3(256), 0, stream, features,
                       fst_w, cnt, tlist, wlist, out);
  }
}

// Round 4
// 192.995 us; speedup vs baseline: 4.7460x; 1.2559x over previous
//
#include <hip/hip_runtime.h>
#include <math.h>

#define B_N 2048
#define F_N 512
#define H_N 256
#define E_N 64

typedef __attribute__((ext_vector_type(8))) short short8;
typedef __attribute__((ext_vector_type(4))) float f32x4;
typedef __attribute__((ext_vector_type(4))) unsigned short ushort4v;

static __device__ __forceinline__ unsigned short bf16_rne(float x) {
  unsigned u = __float_as_uint(x);
  unsigned r = (u + 0x7FFFu + ((u >> 16) & 1u)) >> 16;
  return (unsigned short)r;
}
static __device__ __forceinline__ float bf16_to_f(unsigned short h) {
  return __uint_as_float(((unsigned)h) << 16);
}

// ---------------- K0: prep (transposes, expert norms, coef, zero counts) ----
__global__ __launch_bounds__(256) void k0_prep(
    const float* __restrict__ proj_w, const float* __restrict__ expert_emb,
    const float* __restrict__ expert_features, const float* __restrict__ trust,
    const float* __restrict__ dt, float* __restrict__ pwT,
    float* __restrict__ embT, float* __restrict__ enT,
    float* __restrict__ coef, int* __restrict__ cnt) {
  int bid = blockIdx.x, tid = threadIdx.x;
  if (bid < 512) {
    int idx = bid * 256 + tid;
    int f = idx >> 8, h = idx & 255;
    pwT[idx] = proj_w[h * 512 + f];
    if (bid == 0 && tid < E_N) cnt[tid] = 0;
  } else {
    int e = bid - 512;  // 0..63
    float v0 = expert_features[e * 512 + tid];
    float v1 = expert_features[e * 512 + tid + 256];
    float ss = v0 * v0 + v1 * v1;
    #pragma unroll
    for (int off = 32; off; off >>= 1) ss += __shfl_xor(ss, off);
    __shared__ float parts[4];
    if ((tid & 63) == 0) parts[tid >> 6] = ss;
    __syncthreads();
    float tot = parts[0] + parts[1] + parts[2] + parts[3];
    float inv = 1.0f / fmaxf(sqrtf(tot), 1e-8f);
    enT[tid * 64 + e] = v0 * inv;
    enT[(tid + 256) * 64 + e] = v1 * inv;
    embT[tid * 64 + e] = expert_emb[e * 256 + tid];
    if (tid == 0) {
      float st = fmaxf(0.1f, expf(-0.005f * dt[e]));
      coef[e] = trust[e] * st;
    }
  }
}

// ---------------- K0g: Gpack[f][e] = (pwT[f]·embT[:,e], enT[f][e]); gbias ---
__global__ __launch_bounds__(64) void k0g(
    const float* __restrict__ pwT, const float* __restrict__ proj_b,
    const float* __restrict__ embT, const float* __restrict__ enT,
    float* __restrict__ Gpack, float* __restrict__ gbias) {
  __shared__ float row[256];
  int f = blockIdx.x;
  int e = threadIdx.x;  // 0..63
  const float* src = (f < 512) ? (pwT + f * 256) : proj_b;
  *(float4*)&row[e * 4] = *(const float4*)&src[e * 4];
  __syncthreads();
  float g = 0.0f;
  #pragma unroll 8
  for (int h = 0; h < 256; ++h) g = fmaf(row[h], embT[h * 64 + e], g);
  if (f < 512) {
    Gpack[(f * 64 + e) * 2 + 0] = g;
    Gpack[(f * 64 + e) * 2 + 1] = enT[f * 64 + e];
  } else {
    gbias[e] = g;
  }
}

// ---------------- conv: features -> bf16 hi/lo -----------------------------
__global__ __launch_bounds__(256) void k_convF(const float* __restrict__ f,
    unsigned short* __restrict__ Fh, unsigned short* __restrict__ Fl) {
  int i = (blockIdx.x * 256 + threadIdx.x) * 4;
  float4 v = *(const float4*)(f + i);
  float xs[4] = {v.x, v.y, v.z, v.w};
  ushort4v h, l;
  #pragma unroll
  for (int j = 0; j < 4; ++j) {
    unsigned short hh = bf16_rne(xs[j]);
    h[j] = hh;
    l[j] = bf16_rne(xs[j] - bf16_to_f(hh));
  }
  *(ushort4v*)(Fh + i) = h;
  *(ushort4v*)(Fl + i) = l;
}

// ---------------- conv: fst_w -> transposed bf16 hi/lo [e][col][k] ----------
__global__ __launch_bounds__(256) void k_convW(const float* __restrict__ fst_w,
    unsigned short* __restrict__ WhT, unsigned short* __restrict__ WlT) {
  int bid = blockIdx.x;           // 2048 = 64e x 8colblk x 4kblk
  int e = bid >> 5;
  int cb = (bid >> 2) & 7;
  int kb = bid & 3;
  int tid = threadIdx.x;
  int col = cb * 64 + (tid & 63);
  int k0 = kb * 128 + (tid >> 6) * 32;
  const float* src = fst_w + ((size_t)e << 18) + (size_t)k0 * 512 + col;
  size_t dbase = ((size_t)e << 18) + (size_t)col * 512 + k0;
  #pragma unroll
  for (int g = 0; g < 4; ++g) {
    short8 vh, vl;
    #pragma unroll
    for (int i = 0; i < 8; ++i) {
      float x = src[(size_t)(g * 8 + i) * 512];   // lane-coalesced (lane->col)
      unsigned short hh = bf16_rne(x);
      vh[i] = (short)hh;
      vl[i] = (short)bf16_rne(x - bf16_to_f(hh));
    }
    *(short8*)(WhT + dbase + g * 8) = vh;
    *(short8*)(WlT + dbase + g * 8) = vl;
  }
}

// ---------------- K1: score + top-8 + softmax + scatter (8 tok/block) -------
// Uses precomputed Gpack (gate matrix + normalized expert features packed).
__global__ __launch_bounds__(256) void k1_score(
    const float* __restrict__ features, const float* __restrict__ Gpack,
    const float* __restrict__ gbias, const float* __restrict__ coef,
    int* __restrict__ cnt, int* __restrict__ tk_idx, float* __restrict__ tk_w,
    int* __restrict__ tlist, float* __restrict__ wlist) {
  __shared__ float Ft[8][512];  // 16 KB
  int tid = threadIdx.x;
  int b0 = blockIdx.x * 8;

  // stage 8 feature rows, float4-coalesced
  #pragma unroll
  for (int q = 0; q < 4; ++q) {
    int idx = q * 256 + tid;   // 0..1023 float4 slots
    int t = idx >> 7;
    int fo = (idx & 127) * 4;
    *(float4*)&Ft[t][fo] =
        *(const float4*)&features[(size_t)(b0 + t) * 512 + fo];
  }
  __syncthreads();

  int wave = tid >> 6, e = tid & 63;
  float cf = coef[e];
  float gb = gbias[e];
  int t0 = wave * 2, t1 = t0 + 1;

  // two tokens per wave: 512-dot against Gpack (gate) and enT (sim) fused
  float l0 = 0.f, s0 = 0.f, l1 = 0.f, s1 = 0.f;
  #pragma unroll 8
  for (int f = 0; f < 512; ++f) {
    float2 gp = *(const float2*)&Gpack[(f * 64 + e) * 2];  // lane-coalesced
    float f0 = Ft[t0][f];  // LDS broadcast
    float f1 = Ft[t1][f];
    l0 = fmaf(f0, gp.x, l0);
    s0 = fmaf(f0, gp.y, s0);
    l1 = fmaf(f1, gp.x, l1);
    s1 = fmaf(f1, gp.y, s1);
  }
  // feature norms (64-lane butterfly)
  float n0 = 0.f, n1 = 0.f;
  #pragma unroll
  for (int j = 0; j < 8; ++j) {
    float v0 = Ft[t0][e + 64 * j];
    float v1 = Ft[t1][e + 64 * j];
    n0 = fmaf(v0, v0, n0);
    n1 = fmaf(v1, v1, n1);
  }
  #pragma unroll
  for (int off = 32; off; off >>= 1) {
    n0 += __shfl_xor(n0, off);
    n1 += __shfl_xor(n1, off);
  }

  #pragma unroll
  for (int tt = 0; tt < 2; ++tt) {
    float l = tt ? l1 : l0;
    float s = tt ? s1 : s0;
    float nn = tt ? n1 : n0;
    int b = b0 + wave * 2 + tt;
    float inv_n = 1.0f / fmaxf(sqrtf(nn), 1e-8f);
    float gate = 1.0f / (1.0f + expf(-(l + gb) * 0.0625f));
    float sim = fmaxf(s * inv_n, 0.0f);
    float score = gate * sim * cf;

    // top-8: butterfly max with (value desc, index asc) tie-break
    float cur = score;
    float bv[8];
    int bi[8];
    #pragma unroll
    for (int r = 0; r < 8; ++r) {
      float mv = cur;
      int mi = e;
      #pragma unroll
      for (int off = 1; off < 64; off <<= 1) {
        float ov = __shfl_xor(mv, off);
        int oi = __shfl_xor(mi, off);
        if (ov > mv || (ov == mv && oi < mi)) { mv = ov; mi = oi; }
      }
      bv[r] = mv;
      bi[r] = mi;
      if (e == mi) cur = -1.0f;  // scores are >= 0
    }
    float m0 = bv[0];
    float ex[8];
    float sum = 0.0f;
    #pragma unroll
    for (int r = 0; r < 8; ++r) { ex[r] = expf(bv[r] - m0); sum += ex[r]; }
    float isum = 1.0f / sum;

    if (e < 8) {
      int ir = 0; float er = 0.0f;
      switch (e) {
        case 0: ir = bi[0]; er = ex[0]; break;
        case 1: ir = bi[1]; er = ex[1]; break;
        case 2: ir = bi[2]; er = ex[2]; break;
        case 3: ir = bi[3]; er = ex[3]; break;
        case 4: ir = bi[4]; er = ex[4]; break;
        case 5: ir = bi[5]; er = ex[5]; break;
        case 6: ir = bi[6]; er = ex[6]; break;
        case 7: ir = bi[7]; er = ex[7]; break;
      }
      float wr = er * isum;
      int pos = atomicAdd(&cnt[ir], 1);
      tlist[ir * B_N + pos] = b;
      wlist[ir * B_N + pos] = wr;
      tk_idx[b * 8 + e] = ir;
      tk_w[b * 8 + e] = wr;
    }
  }
}

// ---------------- K2: out[b,:] = sum_k w_k * fst_b[e_k,:]  ------------------
__global__ __launch_bounds__(256) void k2_bias(
    const int* __restrict__ tk_idx, const float* __restrict__ tk_w,
    const float* __restrict__ fst_b, float* __restrict__ out) {
  int b = blockIdx.x, tid = threadIdx.x;
  int ir[8];
  float wr[8];
  #pragma unroll
  for (int r = 0; r < 8; ++r) {
    ir[r] = tk_idx[b * 8 + r];
    wr[r] = tk_w[b * 8 + r];
  }
  #pragma unroll
  for (int q = 0; q < 2; ++q) {
    int f = tid + q * 256;
    float a = 0.0f;
    #pragma unroll
    for (int r = 0; r < 8; ++r) a = fmaf(wr[r], fst_b[ir[r] * 512 + f], a);
    out[(size_t)b * 512 + f] = a;
  }
}

// ---------------- K3 (MFMA): gathered per-expert FST, bf16 3-term split -----
// Block: 64 tokens x 128 cols x K=512. 4 waves, wave tile M64xN32.
// LDS single-buffered: Bh/Bl[128][64], Ah/Al[64][64] bf16, XOR-swizzled slots.
__global__ __launch_bounds__(256, 3) void k3_mfma(
    const unsigned short* __restrict__ Fh, const unsigned short* __restrict__ Fl,
    const unsigned short* __restrict__ WhT, const unsigned short* __restrict__ WlT,
    const int* __restrict__ cnt, const int* __restrict__ tlist,
    const float* __restrict__ wlist, float* __restrict__ out) {
  __shared__ unsigned short Bh[128 * 64];
  __shared__ unsigned short Bl[128 * 64];
  __shared__ unsigned short Ah[64 * 64];
  __shared__ unsigned short Al[64 * 64];
  __shared__ int tl[64];
  __shared__ float wl[64];

  int tid = threadIdx.x;
  int e = blockIdx.x & 63;          // expert-minor spread
  int rest = blockIdx.x >> 6;
  int chunk = rest & 3;             // 4 col chunks of 128
  int tile = rest >> 2;             // 0..31 token tiles
  int c0 = chunk * 128;
  int c_e = cnt[e];
  int t0 = tile * 64;
  if (t0 >= c_e) return;

  if (tid < 64) {
    int t = t0 + tid;
    tl[tid] = tlist[e * B_N + (t < c_e ? t : t0)];
    wl[tid] = (t < c_e) ? wlist[e * B_N + t] : 0.0f;
  }
  __syncthreads();

  int wave = tid >> 6, lane = tid & 63;
  const unsigned short* WhT_e = WhT + ((size_t)e << 18);
  const unsigned short* WlT_e = WlT + ((size_t)e << 18);

  size_t bsrc[4];
  int bdst[4];
  #pragma unroll
  for (int i = 0; i < 4; ++i) {
    int cw = wave * 32 + i * 8;
    int cl = cw + (lane >> 3);
    int g = (lane & 7) ^ (cl & 7);
    bsrc[i] = (size_t)(c0 + cl) * 512 + g * 8;
    bdst[i] = cw * 64;
  }
  size_t asrc[2];
  int adst[2];
  #pragma unroll
  for (int j = 0; j < 2; ++j) {
    int tw = wave * 16 + j * 8;
    int tkl = tw + (lane >> 3);
    int g = (lane & 7) ^ (tkl & 7);
    asrc[j] = (size_t)tl[tkl] * 512 + g * 8;
    adst[j] = tw * 64;
  }

  f32x4 acc[4][2];
  #pragma unroll
  for (int mt = 0; mt < 4; ++mt)
    #pragma unroll
    for (int ct = 0; ct < 2; ++ct) acc[mt][ct] = (f32x4){0.f, 0.f, 0.f, 0.f};

  int kg = lane >> 4;
  int mrow = lane & 15;

  #define STAGE(K0S)                                                          \
    do {                                                                      \
      _Pragma("unroll")                                                       \
      for (int i = 0; i < 4; ++i) {                                           \
        __builtin_amdgcn_global_load_lds(                                     \
            (const __attribute__((address_space(1))) void*)(WhT_e + bsrc[i] + (K0S)), \
            (__attribute__((address_space(3))) void*)(Bh + bdst[i]), 16, 0, 0);\
        __builtin_amdgcn_global_load_lds(                                     \
            (const __attribute__((address_space(1))) void*)(WlT_e + bsrc[i] + (K0S)), \
            (__attribute__((address_space(3))) void*)(Bl + bdst[i]), 16, 0, 0);\
      }                                                                       \
      _Pragma("unroll")                                                       \
      for (int j = 0; j < 2; ++j) {                                           \
        __builtin_amdgcn_global_load_lds(                                     \
            (const __attribute__((address_space(1))) void*)(Fh + asrc[j] + (K0S)), \
            (__attribute__((address_space(3))) void*)(Ah + adst[j]), 16, 0, 0);\
        __builtin_amdgcn_global_load_lds(                                     \
            (const __attribute__((address_space(1))) void*)(Fl + asrc[j] + (K0S)), \
            (__attribute__((address_space(3))) void*)(Al + adst[j]), 16, 0, 0);\
      }                                                                       \
    } while (0)

  STAGE(0);
  __syncthreads();

  for (int s = 0; s < 8; ++s) {
    #pragma unroll
    for (int kh = 0; kh < 2; ++kh) {
      int gq = kh * 4 + kg;
      short8 afh[4], afl[4], bfh[2], bfl[2];
      #pragma unroll
      for (int mt = 0; mt < 4; ++mt) {
        int tr = mt * 16 + mrow;
        int off = tr * 64 + ((gq ^ (tr & 7)) * 8);
        afh[mt] = *(const short8*)(Ah + off);
        afl[mt] = *(const short8*)(Al + off);
      }
      #pragma unroll
      for (int ct = 0; ct < 2; ++ct) {
        int cl = wave * 32 + ct * 16 + mrow;
        int off = cl * 64 + ((gq ^ (cl & 7)) * 8);
        bfh[ct] = *(const short8*)(Bh + off);
        bfl[ct] = *(const short8*)(Bl + off);
      }
      #pragma unroll
      for (int mt = 0; mt < 4; ++mt)
        #pragma unroll
        for (int ct = 0; ct < 2; ++ct) {
          acc[mt][ct] = __builtin_amdgcn_mfma_f32_16x16x32_bf16(
              afh[mt], bfh[ct], acc[mt][ct], 0, 0, 0);
          acc[mt][ct] = __builtin_amdgcn_mfma_f32_16x16x32_bf16(
              afh[mt], bfl[ct], acc[mt][ct], 0, 0, 0);
          acc[mt][ct] = __builtin_amdgcn_mfma_f32_16x16x32_bf16(
              afl[mt], bfh[ct], acc[mt][ct], 0, 0, 0);
        }
    }
    __syncthreads();
    if (s < 7) {
      STAGE((s + 1) * 64);
      __syncthreads();
    }
  }
  #undef STAGE

  int rbase = (lane >> 4) * 4;
  #pragma unroll
  for (int mt = 0; mt < 4; ++mt) {
    #pragma unroll
    for (int r = 0; r < 4; ++r) {
      int tloc = mt * 16 + rbase + r;
      float w = wl[tloc];
      if (w != 0.0f) {
        size_t orow = (size_t)tl[tloc] * 512 + c0 + wave * 32 + mrow;
        atomicAdd(out + orow, w * acc[mt][0][r]);
        atomicAdd(out + orow + 16, w * acc[mt][1][r]);
      }
    }
  }
}

// ---------------- K3 fallback (fp32 VALU) -----------------------------------
#define TM 64
#define TN 256
#define KC 16
__global__ __launch_bounds__(256, 2) void k3_fst(
    const float* __restrict__ features, const float* __restrict__ fst_w,
    const int* __restrict__ cnt, const int* __restrict__ tlist,
    const float* __restrict__ wlist, float* __restrict__ out) {
  __shared__ float Ws[2][KC][TN];
  __shared__ float Ft[2][KC][TM];
  __shared__ int tl[TM];
  __shared__ float wl[TM];

  int tid = threadIdx.x;
  int e = blockIdx.x & 63;
  int rest = blockIdx.x >> 6;
  int tile = rest >> 1;
  int ch = rest & 1;
  int c0 = ch * TN;
  int c_e = cnt[e];
  int t0 = tile * TM;
  if (t0 >= c_e) return;

  if (tid < TM) {
    int t = t0 + tid;
    if (t < c_e) {
      tl[tid] = tlist[e * B_N + t];
      wl[tid] = wlist[e * B_N + t];
    } else {
      tl[tid] = tlist[e * B_N + t0];
      wl[tid] = 0.0f;
    }
  }
  __syncthreads();

  const float* fw_e = fst_w + (size_t)e * (512 * 512);
  int wave = tid >> 6, lane = tid & 63;
  int tg = wave * 2 + (lane >> 5);
  int cg = lane & 31;
  int ft_t = tid >> 2;
  int ft_fq = tid & 3;
  const float* ft_src_row = features + (size_t)tl[ft_t] * 512;

  auto stageWs = [&](int kc, int buf) {
    int f0 = kc * KC;
    #pragma unroll
    for (int r = 0; r < 4; ++r) {
      int f = wave * 4 + r;
      const float* src = fw_e + (size_t)(f0 + f) * 512 + c0 + lane * 4;
      __builtin_amdgcn_global_load_lds(
          (const __attribute__((address_space(1))) void*)src,
          (__attribute__((address_space(3))) void*)&Ws[buf][f][0], 16, 0, 0);
    }
  };
  auto loadFt = [&](int kc) -> float4 {
    return *(const float4*)&ft_src_row[kc * KC + ft_fq * 4];
  };
  auto writeFt = [&](float4 v, int buf) {
    Ft[buf][ft_fq * 4 + 0][ft_t] = v.x;
    Ft[buf][ft_fq * 4 + 1][ft_t] = v.y;
    Ft[buf][ft_fq * 4 + 2][ft_t] = v.z;
    Ft[buf][ft_fq * 4 + 3][ft_t] = v.w;
  };

  float acc[8][8];
  #pragma unroll
  for (int j = 0; j < 8; ++j)
    #pragma unroll
    for (int i = 0; i < 8; ++i) acc[j][i] = 0.0f;

  auto compute = [&](int buf) {
    #pragma unroll 4
    for (int f = 0; f < KC; ++f) {
      float4 a0 = *(const float4*)&Ft[buf][f][tg * 8];
      float4 a1 = *(const float4*)&Ft[buf][f][tg * 8 + 4];
      float4 w0 = *(const float4*)&Ws[buf][f][cg * 4];
      float4 w1 = *(const float4*)&Ws[buf][f][cg * 4 + 128];
      float av[8] = {a0.x, a0.y, a0.z, a0.w, a1.x, a1.y, a1.z, a1.w};
      float wv[8] = {w0.x, w0.y, w0.z, w0.w, w1.x, w1.y, w1.z, w1.w};
      #pragma unroll
      for (int j = 0; j < 8; ++j)
        #pragma unroll
        for (int i = 0; i < 8; ++i)
          acc[j][i] = fmaf(av[j], wv[i], acc[j][i]);
    }
  };

  stageWs(0, 0);
  float4 rf = loadFt(0);
  writeFt(rf, 0);
  __syncthreads();

  for (int kc = 0; kc < 32; ++kc) {
    int cb = kc & 1, nb = cb ^ 1;
    float4 rn = make_float4(0.f, 0.f, 0.f, 0.f);
    if (kc < 31) {
      stageWs(kc + 1, nb);
      rn = loadFt(kc + 1);
    }
    compute(cb);
    if (kc < 31) writeFt(rn, nb);
    __syncthreads();
  }

  #pragma unroll
  for (int j = 0; j < 8; ++j) {
    int lt = tg * 8 + j;
    float w = wl[lt];
    if (w != 0.0f) {
      size_t orow = (size_t)tl[lt] * 512 + c0 + cg * 4;
      #pragma unroll
      for (int i = 0; i < 4; ++i) atomicAdd(&out[orow + i], w * acc[j][i]);
      #pragma unroll
      for (int i = 0; i < 4; ++i)
        atomicAdd(&out[orow + 128 + i], w * acc[j][i + 4]);
    }
  }
}

// ---------------- launch ----------------------------------------------------
extern "C" void kernel_launch(void* const* d_in, const int* in_sizes, int n_in,
                              void* d_out, int out_size, void* d_ws,
                              size_t ws_size, hipStream_t stream) {
  const float* features = (const float*)d_in[0];
  const float* proj_w = (const float*)d_in[1];
  const float* proj_b = (const float*)d_in[2];
  const float* expert_emb = (const float*)d_in[3];
  const float* expert_features = (const float*)d_in[4];
  const float* trust = (const float*)d_in[5];
  const float* dt = (const float*)d_in[6];
  const float* fst_w = (const float*)d_in[7];
  const float* fst_b = (const float*)d_in[8];
  float* out = (float*)d_out;

  float* ws = (float*)d_ws;
  float* pwT = ws;                           // 512*256
  float* embT = pwT + 131072;                // 256*64
  float* enT = embT + 16384;                 // 512*64
  float* coef = enT + 32768;                 // 64
  int* cnt = (int*)(coef + 64);              // 64
  int* tk_idx = cnt + 64;                    // 2048*8
  float* tk_w = (float*)(tk_idx + 16384);    // 2048*8
  int* tlist = (int*)(tk_w + 16384);         // 64*2048
  float* wlist = (float*)(tlist + 131072);   // 64*2048
  float* Gpack = wlist + 131072;             // 512*64*2
  float* gbias = Gpack + 65536;              // 64
  unsigned short* Fh = (unsigned short*)(gbias + 64);       // 2048*512
  unsigned short* Fl = Fh + (1 << 20);
  unsigned short* WhT = Fl + (1 << 20);                     // 64*512*512
  unsigned short* WlT = WhT + (1 << 24);
  size_t need = (size_t)((char*)(WlT + (1 << 24)) - (char*)d_ws);
  bool big = ws_size >= need;

  hipLaunchKernelGGL(k0_prep, dim3(576), dim3(256), 0, stream, proj_w,
                     expert_emb, expert_features, trust, dt, pwT, embT, enT,
                     coef, cnt);
  hipLaunchKernelGGL(k0g, dim3(513), dim3(64), 0, stream, pwT, proj_b, embT,
                     enT, Gpack, gbias);
  if (big) {
    hipLaunchKernelGGL(k_convF, dim3(1024), dim3(256), 0, stream, features, Fh,
                       Fl);
    hipLaunchKernelGGL(k_convW, dim3(2048), dim3(256), 0, stream, fst_w, WhT,
                       WlT);
  }
  hipLaunchKernelGGL(k1_score, dim3(256), dim3(256), 0, stream, features,
                     Gpack, gbias, coef, cnt, tk_idx, tk_w, tlist, wlist);
  hipLaunchKernelGGL(k2_bias, dim3(2048), dim3(256), 0, stream, tk_idx, tk_w,
                     fst_b, out);
  if (big) {
    hipLaunchKernelGGL(k3_mfma, dim3(8192), dim3(256), 0, stream, Fh, Fl, WhT,
                       WlT, cnt, tlist, wlist, out);
  } else {
    hipLaunchKernelGGL(k3_fst, dim3(4096), dim3(256), 0, stream, features,
                       fst_w, cnt, tlist, wlist, out);
  }
}